// Round 2
// baseline (1052.858 us; speedup 1.0000x reference)
//
#include <hip/hip_runtime.h>
#include <math.h>

#define C 21
#define H 512
#define W 512
#define HW (H*W)
#define CHW (C*HW)
#define N_ITERS 5
#define RSP 6
#define KSP 13
#define RBI 8
#define KBI 17

// workspace layout (float offsets)
#define KSP_OFF   0
#define KBI_OFF   16
#define NSP_OFF   64
#define NBI_OFF   576
#define M1_OFF    1088
#define M2_OFF    1536
#define S1_OFF    2048   // N_ITERS*C = 105
#define S2_OFF    2176
#define NCOND_OFF 2304   // N_ITERS ints
#define SM_OFF    4096
#define VSP_OFF   (SM_OFF + CHW)
#define VBI_OFF   (VSP_OFF + CHW)
#define SPT_OFF   (VBI_OFF + CHW)
#define UB_OFF    (SPT_OFF + HW)
#define QB_OFF    (UB_OFF + CHW)

__global__ __launch_bounds__(512) void k_setup(float* ws, const float* skw,
                                               const float* bkw, const float* cm) {
  int tid = threadIdx.x;
  if (tid == 0) {
    float s = 0.f;
    for (int i = 0; i < KSP; ++i) {
      float t = (float)(i - RSP);
      float v = expf(-0.5f * (t / 3.0f) * (t / 3.0f));
      ws[KSP_OFF + i] = v; s += v;
    }
    for (int i = 0; i < KSP; ++i) ws[KSP_OFF + i] /= s;
    s = 0.f;
    for (int i = 0; i < KBI; ++i) {
      float t = (float)(i - RBI);
      float v = expf(-0.5f * (t / 160.0f) * (t / 160.0f));
      ws[KBI_OFF + i] = v; s += v;
    }
    for (int i = 0; i < KBI; ++i) ws[KBI_OFF + i] /= s;
  }
  __syncthreads();
  if (tid < H) {
    float nsp = 0.f, nbi = 0.f;
    for (int t = 0; t < KSP; ++t) { int x = tid + t - RSP; if (x >= 0 && x < H) nsp += ws[KSP_OFF + t]; }
    for (int t = 0; t < KBI; ++t) { int x = tid + t - RBI; if (x >= 0 && x < H) nbi += ws[KBI_OFF + t]; }
    ws[NSP_OFF + tid] = nsp;
    ws[NBI_OFF + tid] = nbi;
  }
  if (tid < C * C) {
    int i = tid / C, j = tid % C;
    float m1 = 0.f, m2 = 0.f;
    for (int k = 0; k < C; ++k) {
      m1 += cm[i * C + k] * skw[k * C + j];
      m2 += cm[i * C + k] * bkw[k * C + j];
    }
    ws[M1_OFF + tid] = m1;
    ws[M2_OFF + tid] = m2;
  }
  if (tid < N_ITERS * C) { ws[S1_OFF + tid] = 0.f; ws[S2_OFF + tid] = 0.f; }
  if (tid < N_ITERS) ((int*)(ws + NCOND_OFF))[tid] = 0;
}

__global__ __launch_bounds__(256) void k_spt(const int* __restrict__ sp_map,
                                             int* __restrict__ spt,
                                             int* __restrict__ ncond) {
  int p = blockIdx.x * 256 + threadIdx.x;
  int h = p >> 9, w = p & 511;
  int v = sp_map[w * H + h];
  spt[p] = v;
#pragma unroll
  for (int i = 0; i < N_ITERS; ++i)
    if (v == 250 + 7 * i) atomicAdd(&ncond[i], 1);
}

// (H,W,C) -> (C,H,W), LDS-tiled, all global accesses coalesced
__global__ __launch_bounds__(256) void k_tin(const float* __restrict__ in,
                                             float* __restrict__ outb) {
  __shared__ float t[C * 257];
  int tid = threadIdx.x;
  size_t p0 = (size_t)blockIdx.x * 256;
  size_t fbase = p0 * C;
#pragma unroll
  for (int i = 0; i < C; ++i) {
    int e = i * 256 + tid;
    int p = e / C, c = e % C;
    t[c * 257 + p] = in[fbase + e];
  }
  __syncthreads();
#pragma unroll
  for (int c = 0; c < C; ++c)
    outb[(size_t)c * HW + p0 + tid] = t[c * 257 + tid];
}

// (C,H,W) -> (H,W,C)
__global__ __launch_bounds__(256) void k_tout(const float* __restrict__ qb,
                                              float* __restrict__ out) {
  __shared__ float t[C * 257];
  int tid = threadIdx.x;
  size_t p0 = (size_t)blockIdx.x * 256;
#pragma unroll
  for (int c = 0; c < C; ++c)
    t[c * 257 + tid] = qb[(size_t)c * HW + p0 + tid];
  __syncthreads();
  size_t fbase = p0 * C;
#pragma unroll
  for (int i = 0; i < C; ++i) {
    int e = i * 256 + tid;
    int p = e / C, c = e % C;
    out[fbase + e] = t[c * 257 + p];
  }
}

// input channel-first (C,HW): fully coalesced
__global__ __launch_bounds__(256) void k_softmax(const float* __restrict__ qin,
                                                 float* __restrict__ sm,
                                                 const int* __restrict__ spt,
                                                 float* __restrict__ S1,
                                                 float* __restrict__ S2,
                                                 int sp_id) {
  int p = blockIdx.x * 256 + threadIdx.x;
  float q[C];
  float m = -1e30f;
#pragma unroll
  for (int c = 0; c < C; ++c) { q[c] = qin[c * HW + p]; m = fmaxf(m, q[c]); }
  float s = 0.f;
#pragma unroll
  for (int c = 0; c < C; ++c) { q[c] = expf(q[c] - m); s += q[c]; }
  float inv = 1.f / s;
  float smax = 0.f;
#pragma unroll
  for (int c = 0; c < C; ++c) {
    q[c] = q[c] * inv;
    smax = fmaxf(smax, q[c]);
    sm[c * HW + p] = q[c];
  }
  if (spt[p] == sp_id) {
#pragma unroll
    for (int c = 0; c < C; ++c) {
      atomicAdd(&S1[c], expf(q[c]));
      float A = (q[c] == smax) ? smax : q[c] + smax;
      atomicAdd(&S2[c], expf(A));
    }
  }
}

__global__ __launch_bounds__(256) void k_vblur(const float* __restrict__ sm,
                                               float* __restrict__ vsp,
                                               float* __restrict__ vbi,
                                               const float* __restrict__ ws) {
  __shared__ float ksp[KSP], kbi[KBI];
  int tid = threadIdx.x;
  if (tid < KSP) ksp[tid] = ws[KSP_OFF + tid];
  if (tid < KBI) kbi[tid] = ws[KBI_OFF + tid];
  __syncthreads();
  int w = blockIdx.x * 256 + tid;
  int h0 = blockIdx.y * 8;
  int c = blockIdx.z;
  const float* s = sm + (size_t)c * HW;
  float rowv[24];
#pragma unroll
  for (int j = 0; j < 24; ++j) {
    int hh = h0 - 8 + j;
    rowv[j] = (hh >= 0 && hh < H) ? s[hh * W + w] : 0.f;
  }
#pragma unroll
  for (int o = 0; o < 8; ++o) {
    float a = 0.f, b = 0.f;
#pragma unroll
    for (int t = 0; t < KSP; ++t) a += ksp[t] * rowv[o + 2 + t];
#pragma unroll
    for (int t = 0; t < KBI; ++t) b += kbi[t] * rowv[o + t];
    size_t idx = (size_t)c * HW + (size_t)(h0 + o) * W + w;
    vsp[idx] = a;
    vbi[idx] = b;
  }
}

__global__ __launch_bounds__(256) void k_hcombine(
    const float* __restrict__ vsp, const float* __restrict__ vbi,
    const float* __restrict__ sm, const float* __restrict__ u,
    const int* __restrict__ spt, float* __restrict__ out,
    const float* __restrict__ ws, const float* __restrict__ loww,
    const float* __restrict__ highw, int sp_id, int iter) {
  __shared__ float lm1[441], lm2[441], lksp[KSP], lkbi[KBI];
  __shared__ float tsp[272], tbi[272];
  int tid = threadIdx.x;
  for (int i = tid; i < 441; i += 256) { lm1[i] = ws[M1_OFF + i]; lm2[i] = ws[M2_OFF + i]; }
  if (tid < KSP) lksp[tid] = ws[KSP_OFF + tid];
  if (tid < KBI) lkbi[tid] = ws[KBI_OFF + tid];
  int w0 = blockIdx.x * 256;
  int h = blockIdx.y;
  int w = w0 + tid;
  int p = h * W + w;
  float inv_nsp = 1.f / (ws[NSP_OFF + h] * ws[NSP_OFF + w]);
  float inv_nbi = 1.f / (ws[NBI_OFF + h] * ws[NBI_OFF + w]);
  float pw[C];
#pragma unroll
  for (int j = 0; j < C; ++j) pw[j] = 0.f;
  for (int c = 0; c < C; ++c) {
    __syncthreads();
    size_t base = (size_t)c * HW + (size_t)h * W;
    for (int i = tid; i < 272; i += 256) {
      int gw = w0 - 8 + i;
      bool ok = (gw >= 0 && gw < W);
      tsp[i] = ok ? vsp[base + gw] : 0.f;
      tbi[i] = ok ? vbi[base + gw] : 0.f;
    }
    __syncthreads();
    float a = 0.f, b = 0.f;
#pragma unroll
    for (int t = 0; t < KSP; ++t) a += lksp[t] * tsp[tid + 2 + t];
#pragma unroll
    for (int t = 0; t < KBI; ++t) b += lkbi[t] * tbi[tid + t];
    a *= inv_nsp;
    b *= inv_nbi;
#pragma unroll
    for (int j = 0; j < C; ++j) pw[j] += lm1[j * C + c] * a + lm2[j * C + c] * b;
  }
  float high0 = highw[0], high1 = highw[1];
  // u and out are channel-first (C,HW): coalesced
  if (spt[p] == sp_id) {
    float smv[C];
    float smax = 0.f;
#pragma unroll
    for (int c = 0; c < C; ++c) { smv[c] = sm[c * HW + p]; smax = fmaxf(smax, smv[c]); }
    int n = ((const int*)(ws + NCOND_OFF))[iter];
    float HWn = (float)(HW - n);
#pragma unroll
    for (int c = 0; c < C; ++c) {
      float Bsp = logf(HWn + ws[S1_OFF + iter * C + c]);
      float Bco = logf(HWn + ws[S2_OFF + iter * C + c]);
      float qm = (smv[c] == 0.f) ? 1.f : smv[c];
      float A = (smv[c] == smax) ? smax : smv[c] + smax;
      float qs = (A == 0.f) ? 1.f : A;
      float ft = Bsp / qm;
      float ft2 = Bco / qs;
      float cont = loww[c] * ft + high0 * (1.f - ft) + loww[C + c] * ft2 + high1 * (1.f - ft2);
      out[c * HW + p] = u[c * HW + p] - pw[c] - cont;
    }
  } else {
    float cc = high0 + high1;
#pragma unroll
    for (int c = 0; c < C; ++c) out[c * HW + p] = u[c * HW + p] - pw[c] - cc;
  }
}

extern "C" void kernel_launch(void* const* d_in, const int* in_sizes, int n_in,
                              void* d_out, int out_size, void* d_ws, size_t ws_size,
                              hipStream_t stream) {
  const float* unaries = (const float*)d_in[0];
  const int* sp_map = (const int*)d_in[2];
  const float* skw = (const float*)d_in[3];
  const float* bkw = (const float*)d_in[4];
  const float* loww = (const float*)d_in[5];
  const float* highw = (const float*)d_in[6];
  const float* cm = (const float*)d_in[7];
  float* out = (float*)d_out;
  float* ws = (float*)d_ws;
  float* smb = ws + SM_OFF;
  float* vsp = ws + VSP_OFF;
  float* vbi = ws + VBI_OFF;
  int* spt = (int*)(ws + SPT_OFF);
  float* ubuf = ws + UB_OFF;
  float* qbuf = ws + QB_OFF;
  int* ncond = (int*)(ws + NCOND_OFF);

  k_setup<<<1, 512, 0, stream>>>(ws, skw, bkw, cm);
  k_spt<<<HW / 256, 256, 0, stream>>>(sp_map, spt, ncond);
  k_tin<<<HW / 256, 256, 0, stream>>>(unaries, ubuf);
  for (int i = 0; i < N_ITERS; ++i) {
    int sp_id = 250 + 7 * i;
    const float* qin = (i == 0) ? ubuf : qbuf;
    k_softmax<<<HW / 256, 256, 0, stream>>>(qin, smb, spt,
                                            ws + S1_OFF + i * C, ws + S2_OFF + i * C, sp_id);
    k_vblur<<<dim3(2, 64, C), 256, 0, stream>>>(smb, vsp, vbi, ws);
    k_hcombine<<<dim3(2, 512), 256, 0, stream>>>(vsp, vbi, smb, ubuf, spt, qbuf,
                                                 ws, loww, highw, sp_id, i);
  }
  k_tout<<<HW / 256, 256, 0, stream>>>(qbuf, out);
}

// Round 3
// 1029.290 us; speedup vs baseline: 1.0229x; 1.0229x over previous
//
#include <hip/hip_runtime.h>
#include <math.h>

#define C 21
#define H 512
#define W 512
#define HW (H*W)
#define CHW (C*HW)
#define N_ITERS 5
#define RSP 6
#define KSP 13
#define RBI 8
#define KBI 17

// workspace layout (float offsets)
#define KSP_OFF   0
#define KBI_OFF   16
#define NSP_OFF   64
#define NBI_OFF   576
#define M1_OFF    1088
#define M2_OFF    1536
#define S1_OFF    2048   // N_ITERS*C = 105
#define S2_OFF    2176
#define NCOND_OFF 2304   // N_ITERS ints
#define SM_OFF    4096
#define VSP_OFF   (SM_OFF + CHW)
#define VBI_OFF   (VSP_OFF + CHW)
#define SPT_OFF   (VBI_OFF + CHW)
#define UB_OFF    (SPT_OFF + HW)
#define QB_OFF    (UB_OFF + CHW)

#define REP8(F) F(0) F(1) F(2) F(3) F(4) F(5) F(6) F(7)
#define REP21(F) F(0) F(1) F(2) F(3) F(4) F(5) F(6) F(7) F(8) F(9) F(10) \
                 F(11) F(12) F(13) F(14) F(15) F(16) F(17) F(18) F(19) F(20)

__global__ __launch_bounds__(512) void k_setup(float* ws, const float* skw,
                                               const float* bkw, const float* cm) {
  int tid = threadIdx.x;
  if (tid == 0) {
    float s = 0.f;
    for (int i = 0; i < KSP; ++i) {
      float t = (float)(i - RSP);
      float v = expf(-0.5f * (t / 3.0f) * (t / 3.0f));
      ws[KSP_OFF + i] = v; s += v;
    }
    for (int i = 0; i < KSP; ++i) ws[KSP_OFF + i] /= s;
    s = 0.f;
    for (int i = 0; i < KBI; ++i) {
      float t = (float)(i - RBI);
      float v = expf(-0.5f * (t / 160.0f) * (t / 160.0f));
      ws[KBI_OFF + i] = v; s += v;
    }
    for (int i = 0; i < KBI; ++i) ws[KBI_OFF + i] /= s;
  }
  __syncthreads();
  if (tid < H) {
    float nsp = 0.f, nbi = 0.f;
    for (int t = 0; t < KSP; ++t) { int x = tid + t - RSP; if (x >= 0 && x < H) nsp += ws[KSP_OFF + t]; }
    for (int t = 0; t < KBI; ++t) { int x = tid + t - RBI; if (x >= 0 && x < H) nbi += ws[KBI_OFF + t]; }
    ws[NSP_OFF + tid] = nsp;
    ws[NBI_OFF + tid] = nbi;
  }
  if (tid < C * C) {
    int i = tid / C, j = tid % C;
    float m1 = 0.f, m2 = 0.f;
    for (int k = 0; k < C; ++k) {
      m1 += cm[i * C + k] * skw[k * C + j];
      m2 += cm[i * C + k] * bkw[k * C + j];
    }
    ws[M1_OFF + tid] = m1;
    ws[M2_OFF + tid] = m2;
  }
  if (tid < N_ITERS * C) { ws[S1_OFF + tid] = 0.f; ws[S2_OFF + tid] = 0.f; }
  if (tid < N_ITERS) ((int*)(ws + NCOND_OFF))[tid] = 0;
}

__global__ __launch_bounds__(256) void k_spt(const int* __restrict__ sp_map,
                                             int* __restrict__ spt,
                                             int* __restrict__ ncond) {
  int p = blockIdx.x * 256 + threadIdx.x;
  int h = p >> 9, w = p & 511;
  int v = sp_map[w * H + h];
  spt[p] = v;
#pragma unroll
  for (int i = 0; i < N_ITERS; ++i)
    if (v == 250 + 7 * i) atomicAdd(&ncond[i], 1);
}

// (H,W,C) -> (C,H,W), LDS-tiled, all global accesses coalesced
__global__ __launch_bounds__(256) void k_tin(const float* __restrict__ in,
                                             float* __restrict__ outb) {
  __shared__ float t[C * 257];
  int tid = threadIdx.x;
  size_t p0 = (size_t)blockIdx.x * 256;
  size_t fbase = p0 * C;
#pragma unroll
  for (int i = 0; i < C; ++i) {
    int e = i * 256 + tid;
    int p = e / C, c = e % C;
    t[c * 257 + p] = in[fbase + e];
  }
  __syncthreads();
#pragma unroll
  for (int c = 0; c < C; ++c)
    outb[(size_t)c * HW + p0 + tid] = t[c * 257 + tid];
}

// (C,H,W) -> (H,W,C)
__global__ __launch_bounds__(256) void k_tout(const float* __restrict__ qb,
                                              float* __restrict__ out) {
  __shared__ float t[C * 257];
  int tid = threadIdx.x;
  size_t p0 = (size_t)blockIdx.x * 256;
#pragma unroll
  for (int c = 0; c < C; ++c)
    t[c * 257 + tid] = qb[(size_t)c * HW + p0 + tid];
  __syncthreads();
  size_t fbase = p0 * C;
#pragma unroll
  for (int i = 0; i < C; ++i) {
    int e = i * 256 + tid;
    int p = e / C, c = e % C;
    out[fbase + e] = t[c * 257 + p];
  }
}

// channel-first (C,HW), all named scalars (no per-thread arrays -> no scratch)
__global__ __launch_bounds__(256) void k_softmax(const float* __restrict__ qin,
                                                 float* __restrict__ smb,
                                                 const int* __restrict__ spt,
                                                 float* __restrict__ S1,
                                                 float* __restrict__ S2,
                                                 int sp_id) {
  int p = blockIdx.x * 256 + threadIdx.x;
  float m = -1e30f;
#define LOADQ(i) float q##i = qin[(i) * HW + p]; m = fmaxf(m, q##i);
  REP21(LOADQ)
#undef LOADQ
  float s = 0.f;
#define EXPQ(i) q##i = expf(q##i - m); s += q##i;
  REP21(EXPQ)
#undef EXPQ
  float inv = 1.f / s;
  float smax = 0.f;
#define NORMQ(i) q##i *= inv; smax = fmaxf(smax, q##i); smb[(i) * HW + p] = q##i;
  REP21(NORMQ)
#undef NORMQ
  if (spt[p] == sp_id) {
#define ATOMQ(i) { atomicAdd(&S1[i], expf(q##i)); \
                   float A = (q##i == smax) ? smax : q##i + smax; \
                   atomicAdd(&S2[i], expf(A)); }
    REP21(ATOMQ)
#undef ATOMQ
  }
}

// vertical dual blur: scatter-accumulate into 16 named accumulators
__global__ __launch_bounds__(256) void k_vblur(const float* __restrict__ smb,
                                               float* __restrict__ vsp,
                                               float* __restrict__ vbi,
                                               const float* __restrict__ ws) {
  __shared__ float ksp[KSP], kbi[KBI];
  int tid = threadIdx.x;
  if (tid < KSP) ksp[tid] = ws[KSP_OFF + tid];
  if (tid < KBI) kbi[tid] = ws[KBI_OFF + tid];
  __syncthreads();
  int w = blockIdx.x * 256 + tid;
  int h0 = blockIdx.y * 8;
  int c = blockIdx.z;
  const float* s = smb + (size_t)c * HW;
#define DECLA(o) float a##o = 0.f; float b##o = 0.f;
  REP8(DECLA)
#undef DECLA
#pragma unroll
  for (int j = 0; j < 24; ++j) {
    int hh = h0 - 8 + j;
    float v = (hh >= 0 && hh < H) ? s[hh * W + w] : 0.f;
#define ACCA(o) { int t = j - 2 - (o); if (t >= 0 && t < KSP) a##o += ksp[t] * v; }
    REP8(ACCA)
#undef ACCA
#define ACCB(o) { int t = j - (o); if (t >= 0 && t < KBI) b##o += kbi[t] * v; }
    REP8(ACCB)
#undef ACCB
  }
#define STORV(o) { size_t idx = (size_t)c * HW + (size_t)(h0 + (o)) * W + w; \
                   vsp[idx] = a##o; vbi[idx] = b##o; }
  REP8(STORV)
#undef STORV
}

__global__ __launch_bounds__(256) void k_hcombine(
    const float* __restrict__ vsp, const float* __restrict__ vbi,
    const float* __restrict__ smb, const float* __restrict__ u,
    const int* __restrict__ spt, float* __restrict__ out,
    const float* __restrict__ ws, const float* __restrict__ loww,
    const float* __restrict__ highw, int sp_id, int iter) {
  __shared__ float lm1[441], lm2[441], lksp[KSP], lkbi[KBI];
  __shared__ float tsp[272], tbi[272];
  int tid = threadIdx.x;
  for (int i = tid; i < 441; i += 256) { lm1[i] = ws[M1_OFF + i]; lm2[i] = ws[M2_OFF + i]; }
  if (tid < KSP) lksp[tid] = ws[KSP_OFF + tid];
  if (tid < KBI) lkbi[tid] = ws[KBI_OFF + tid];
  int w0 = blockIdx.x * 256;
  int h = blockIdx.y;
  int w = w0 + tid;
  int p = h * W + w;
  float inv_nsp = 1.f / (ws[NSP_OFF + h] * ws[NSP_OFF + w]);
  float inv_nbi = 1.f / (ws[NBI_OFF + h] * ws[NBI_OFF + w]);
#define DECLPW(i) float pw##i = 0.f;
  REP21(DECLPW)
#undef DECLPW
  for (int c = 0; c < C; ++c) {
    __syncthreads();
    size_t base = (size_t)c * HW + (size_t)h * W;
    for (int i = tid; i < 272; i += 256) {
      int gw = w0 - 8 + i;
      bool ok = (gw >= 0 && gw < W);
      tsp[i] = ok ? vsp[base + gw] : 0.f;
      tbi[i] = ok ? vbi[base + gw] : 0.f;
    }
    __syncthreads();
    float a = 0.f, b = 0.f;
#pragma unroll
    for (int t = 0; t < KSP; ++t) a += lksp[t] * tsp[tid + 2 + t];
#pragma unroll
    for (int t = 0; t < KBI; ++t) b += lkbi[t] * tbi[tid + t];
    a *= inv_nsp;
    b *= inv_nbi;
#define ACCPW(i) pw##i += lm1[(i) * C + c] * a + lm2[(i) * C + c] * b;
    REP21(ACCPW)
#undef ACCPW
  }
  float high0 = highw[0], high1 = highw[1];
  if (spt[p] == sp_id) {
    float smax = 0.f;
#define LSM(i) float v##i = smb[(i) * HW + p]; smax = fmaxf(smax, v##i);
    REP21(LSM)
#undef LSM
    int n = ((const int*)(ws + NCOND_OFF))[iter];
    float HWn = (float)(HW - n);
#define CONTQ(i) { float Bsp = logf(HWn + ws[S1_OFF + iter * C + (i)]); \
                   float Bco = logf(HWn + ws[S2_OFF + iter * C + (i)]); \
                   float qm = (v##i == 0.f) ? 1.f : v##i; \
                   float A = (v##i == smax) ? smax : v##i + smax; \
                   float qs = (A == 0.f) ? 1.f : A; \
                   float ft = Bsp / qm; \
                   float ft2 = Bco / qs; \
                   float cont = loww[(i)] * ft + high0 * (1.f - ft) \
                              + loww[C + (i)] * ft2 + high1 * (1.f - ft2); \
                   out[(i) * HW + p] = u[(i) * HW + p] - pw##i - cont; }
    REP21(CONTQ)
#undef CONTQ
  } else {
    float cc = high0 + high1;
#define OUTW(i) out[(i) * HW + p] = u[(i) * HW + p] - pw##i - cc;
    REP21(OUTW)
#undef OUTW
  }
}

extern "C" void kernel_launch(void* const* d_in, const int* in_sizes, int n_in,
                              void* d_out, int out_size, void* d_ws, size_t ws_size,
                              hipStream_t stream) {
  const float* unaries = (const float*)d_in[0];
  const int* sp_map = (const int*)d_in[2];
  const float* skw = (const float*)d_in[3];
  const float* bkw = (const float*)d_in[4];
  const float* loww = (const float*)d_in[5];
  const float* highw = (const float*)d_in[6];
  const float* cm = (const float*)d_in[7];
  float* out = (float*)d_out;
  float* ws = (float*)d_ws;
  float* smb = ws + SM_OFF;
  float* vsp = ws + VSP_OFF;
  float* vbi = ws + VBI_OFF;
  int* spt = (int*)(ws + SPT_OFF);
  float* ubuf = ws + UB_OFF;
  float* qbuf = ws + QB_OFF;
  int* ncond = (int*)(ws + NCOND_OFF);

  k_setup<<<1, 512, 0, stream>>>(ws, skw, bkw, cm);
  k_spt<<<HW / 256, 256, 0, stream>>>(sp_map, spt, ncond);
  k_tin<<<HW / 256, 256, 0, stream>>>(unaries, ubuf);
  for (int i = 0; i < N_ITERS; ++i) {
    int sp_id = 250 + 7 * i;
    const float* qin = (i == 0) ? ubuf : qbuf;
    k_softmax<<<HW / 256, 256, 0, stream>>>(qin, smb, spt,
                                            ws + S1_OFF + i * C, ws + S2_OFF + i * C, sp_id);
    k_vblur<<<dim3(2, 64, C), 256, 0, stream>>>(smb, vsp, vbi, ws);
    k_hcombine<<<dim3(2, 512), 256, 0, stream>>>(vsp, vbi, smb, ubuf, spt, qbuf,
                                                 ws, loww, highw, sp_id, i);
  }
  k_tout<<<HW / 256, 256, 0, stream>>>(qbuf, out);
}

// Round 4
// 515.098 us; speedup vs baseline: 2.0440x; 1.9982x over previous
//
#include <hip/hip_runtime.h>
#include <math.h>

#define C 21
#define H 512
#define W 512
#define HW (H*W)
#define CHW (C*HW)
#define N_ITERS 5
#define RSP 6
#define KSP 13
#define RBI 8
#define KBI 17
#define LIST_CAP 4096

// workspace layout (float offsets)
#define KSP_OFF   0
#define KBI_OFF   16
#define NSP_OFF   64
#define NBI_OFF   576
#define M1_OFF    1088
#define M2_OFF    1536
#define NCOND_OFF 2048   // N_ITERS ints
#define BSP_OFF   2112   // N_ITERS*C
#define BCO_OFF   2240   // N_ITERS*C
#define LIST_OFF  2368   // N_ITERS*LIST_CAP ints
#define SM_OFF    24576
#define VSP_OFF   (SM_OFF + CHW)
#define VBI_OFF   (VSP_OFF + CHW)
#define SPT_OFF   (VBI_OFF + CHW)
#define UB_OFF    (SPT_OFF + HW)
#define QB_OFF    (UB_OFF + CHW)

#define REP8(F) F(0) F(1) F(2) F(3) F(4) F(5) F(6) F(7)
#define REP21(F) F(0) F(1) F(2) F(3) F(4) F(5) F(6) F(7) F(8) F(9) F(10) \
                 F(11) F(12) F(13) F(14) F(15) F(16) F(17) F(18) F(19) F(20)

__global__ __launch_bounds__(512) void k_setup(float* ws, const float* skw,
                                               const float* bkw, const float* cm) {
  int tid = threadIdx.x;
  if (tid == 0) {
    float s = 0.f;
    for (int i = 0; i < KSP; ++i) {
      float t = (float)(i - RSP);
      float v = expf(-0.5f * (t / 3.0f) * (t / 3.0f));
      ws[KSP_OFF + i] = v; s += v;
    }
    for (int i = 0; i < KSP; ++i) ws[KSP_OFF + i] /= s;
    s = 0.f;
    for (int i = 0; i < KBI; ++i) {
      float t = (float)(i - RBI);
      float v = expf(-0.5f * (t / 160.0f) * (t / 160.0f));
      ws[KBI_OFF + i] = v; s += v;
    }
    for (int i = 0; i < KBI; ++i) ws[KBI_OFF + i] /= s;
  }
  __syncthreads();
  if (tid < H) {
    float nsp = 0.f, nbi = 0.f;
    for (int t = 0; t < KSP; ++t) { int x = tid + t - RSP; if (x >= 0 && x < H) nsp += ws[KSP_OFF + t]; }
    for (int t = 0; t < KBI; ++t) { int x = tid + t - RBI; if (x >= 0 && x < H) nbi += ws[KBI_OFF + t]; }
    ws[NSP_OFF + tid] = nsp;
    ws[NBI_OFF + tid] = nbi;
  }
  if (tid < C * C) {
    int i = tid / C, j = tid % C;
    float m1 = 0.f, m2 = 0.f;
    for (int k = 0; k < C; ++k) {
      m1 += cm[i * C + k] * skw[k * C + j];
      m2 += cm[i * C + k] * bkw[k * C + j];
    }
    ws[M1_OFF + tid] = m1;
    ws[M2_OFF + tid] = m2;
  }
  if (tid < N_ITERS) ((int*)(ws + NCOND_OFF))[tid] = 0;
}

// build transposed sp map AND compact per-sp_id pixel lists (runs once per call)
__global__ __launch_bounds__(256) void k_spt(const int* __restrict__ sp_map,
                                             int* __restrict__ spt,
                                             int* __restrict__ ncond,
                                             int* __restrict__ list) {
  int p = blockIdx.x * 256 + threadIdx.x;
  int h = p >> 9, w = p & 511;
  int v = sp_map[w * H + h];
  spt[p] = v;
#pragma unroll
  for (int i = 0; i < N_ITERS; ++i)
    if (v == 250 + 7 * i) {
      int slot = atomicAdd(&ncond[i], 1);
      if (slot < LIST_CAP) list[i * LIST_CAP + slot] = p;
    }
}

// (H,W,C) -> (C,H,W), LDS-tiled, all global accesses coalesced
__global__ __launch_bounds__(256) void k_tin(const float* __restrict__ in,
                                             float* __restrict__ outb) {
  __shared__ float t[C * 257];
  int tid = threadIdx.x;
  size_t p0 = (size_t)blockIdx.x * 256;
  size_t fbase = p0 * C;
#pragma unroll
  for (int i = 0; i < C; ++i) {
    int e = i * 256 + tid;
    int p = e / C, c = e % C;
    t[c * 257 + p] = in[fbase + e];
  }
  __syncthreads();
#pragma unroll
  for (int c = 0; c < C; ++c)
    outb[(size_t)c * HW + p0 + tid] = t[c * 257 + tid];
}

// (C,H,W) -> (H,W,C)
__global__ __launch_bounds__(256) void k_tout(const float* __restrict__ qb,
                                              float* __restrict__ out) {
  __shared__ float t[C * 257];
  int tid = threadIdx.x;
  size_t p0 = (size_t)blockIdx.x * 256;
#pragma unroll
  for (int c = 0; c < C; ++c)
    t[c * 257 + tid] = qb[(size_t)c * HW + p0 + tid];
  __syncthreads();
  size_t fbase = p0 * C;
#pragma unroll
  for (int i = 0; i < C; ++i) {
    int e = i * 256 + tid;
    int p = e / C, c = e % C;
    out[fbase + e] = t[c * 257 + p];
  }
}

// pure softmax, channel-first (C,HW): no atomics, no spt
__global__ __launch_bounds__(256) void k_softmax(const float* __restrict__ qin,
                                                 float* __restrict__ smb) {
  int p = blockIdx.x * 256 + threadIdx.x;
  float m = -1e30f;
#define LOADQ(i) float q##i = qin[(i) * HW + p]; m = fmaxf(m, q##i);
  REP21(LOADQ)
#undef LOADQ
  float s = 0.f;
#define EXPQ(i) q##i = expf(q##i - m); s += q##i;
  REP21(EXPQ)
#undef EXPQ
  float inv = 1.f / s;
#define NORMQ(i) smb[(i) * HW + p] = q##i * inv;
  REP21(NORMQ)
#undef NORMQ
}

// per-channel clique reductions over the compacted cond-pixel list (no atomics)
__global__ __launch_bounds__(256) void k_clique(const float* __restrict__ smb,
                                                float* __restrict__ ws, int iter) {
  int c = blockIdx.x;
  int tid = threadIdx.x;
  const int* ncond = (const int*)(ws + NCOND_OFF);
  const int* list = (const int*)(ws + LIST_OFF) + iter * LIST_CAP;
  int n = ncond[iter];
  if (n > LIST_CAP) n = LIST_CAP;
  float e1 = 0.f, e2 = 0.f;
  for (int j = tid; j < n; j += 256) {
    int p = list[j];
    float smax = 0.f;
#define SMX(i) { float t = smb[(i) * HW + p]; smax = fmaxf(smax, t); }
    REP21(SMX)
#undef SMX
    float vc = smb[c * HW + p];
    e1 += expf(vc);
    float A = (vc == smax) ? smax : vc + smax;
    e2 += expf(A);
  }
#pragma unroll
  for (int off = 32; off; off >>= 1) {
    e1 += __shfl_xor(e1, off);
    e2 += __shfl_xor(e2, off);
  }
  __shared__ float r1[4], r2[4];
  int lane = tid & 63, wid = tid >> 6;
  if (lane == 0) { r1[wid] = e1; r2[wid] = e2; }
  __syncthreads();
  if (tid == 0) {
    float s1 = r1[0] + r1[1] + r1[2] + r1[3];
    float s2 = r2[0] + r2[1] + r2[2] + r2[3];
    float HWn = (float)(HW - n);
    ws[BSP_OFF + iter * C + c] = logf(HWn + s1);
    ws[BCO_OFF + iter * C + c] = logf(HWn + s2);
  }
}

// vertical dual blur: scatter-accumulate into 16 named accumulators
__global__ __launch_bounds__(256) void k_vblur(const float* __restrict__ smb,
                                               float* __restrict__ vsp,
                                               float* __restrict__ vbi,
                                               const float* __restrict__ ws) {
  __shared__ float ksp[KSP], kbi[KBI];
  int tid = threadIdx.x;
  if (tid < KSP) ksp[tid] = ws[KSP_OFF + tid];
  if (tid < KBI) kbi[tid] = ws[KBI_OFF + tid];
  __syncthreads();
  int w = blockIdx.x * 256 + tid;
  int h0 = blockIdx.y * 8;
  int c = blockIdx.z;
  const float* s = smb + (size_t)c * HW;
#define DECLA(o) float a##o = 0.f; float b##o = 0.f;
  REP8(DECLA)
#undef DECLA
#pragma unroll
  for (int j = 0; j < 24; ++j) {
    int hh = h0 - 8 + j;
    float v = (hh >= 0 && hh < H) ? s[hh * W + w] : 0.f;
#define ACCA(o) { int t = j - 2 - (o); if (t >= 0 && t < KSP) a##o += ksp[t] * v; }
    REP8(ACCA)
#undef ACCA
#define ACCB(o) { int t = j - (o); if (t >= 0 && t < KBI) b##o += kbi[t] * v; }
    REP8(ACCB)
#undef ACCB
  }
#define STORV(o) { size_t idx = (size_t)c * HW + (size_t)(h0 + (o)) * W + w; \
                   vsp[idx] = a##o; vbi[idx] = b##o; }
  REP8(STORV)
#undef STORV
}

__global__ __launch_bounds__(256) void k_hcombine(
    const float* __restrict__ vsp, const float* __restrict__ vbi,
    const float* __restrict__ smb, const float* __restrict__ u,
    const int* __restrict__ spt, float* __restrict__ out,
    const float* __restrict__ ws, const float* __restrict__ loww,
    const float* __restrict__ highw, int sp_id, int iter) {
  __shared__ float lm1[441], lm2[441], lksp[KSP], lkbi[KBI];
  __shared__ float tsp[272], tbi[272];
  int tid = threadIdx.x;
  for (int i = tid; i < 441; i += 256) { lm1[i] = ws[M1_OFF + i]; lm2[i] = ws[M2_OFF + i]; }
  if (tid < KSP) lksp[tid] = ws[KSP_OFF + tid];
  if (tid < KBI) lkbi[tid] = ws[KBI_OFF + tid];
  int w0 = blockIdx.x * 256;
  int h = blockIdx.y;
  int w = w0 + tid;
  int p = h * W + w;
  float inv_nsp = 1.f / (ws[NSP_OFF + h] * ws[NSP_OFF + w]);
  float inv_nbi = 1.f / (ws[NBI_OFF + h] * ws[NBI_OFF + w]);
#define DECLPW(i) float pw##i = 0.f;
  REP21(DECLPW)
#undef DECLPW
  for (int c = 0; c < C; ++c) {
    __syncthreads();
    size_t base = (size_t)c * HW + (size_t)h * W;
    for (int i = tid; i < 272; i += 256) {
      int gw = w0 - 8 + i;
      bool ok = (gw >= 0 && gw < W);
      tsp[i] = ok ? vsp[base + gw] : 0.f;
      tbi[i] = ok ? vbi[base + gw] : 0.f;
    }
    __syncthreads();
    float a = 0.f, b = 0.f;
#pragma unroll
    for (int t = 0; t < KSP; ++t) a += lksp[t] * tsp[tid + 2 + t];
#pragma unroll
    for (int t = 0; t < KBI; ++t) b += lkbi[t] * tbi[tid + t];
    a *= inv_nsp;
    b *= inv_nbi;
#define ACCPW(i) pw##i += lm1[(i) * C + c] * a + lm2[(i) * C + c] * b;
    REP21(ACCPW)
#undef ACCPW
  }
  float high0 = highw[0], high1 = highw[1];
  if (spt[p] == sp_id) {
    float smax = 0.f;
#define LSM(i) float v##i = smb[(i) * HW + p]; smax = fmaxf(smax, v##i);
    REP21(LSM)
#undef LSM
#define CONTQ(i) { float Bsp = ws[BSP_OFF + iter * C + (i)]; \
                   float Bco = ws[BCO_OFF + iter * C + (i)]; \
                   float qm = (v##i == 0.f) ? 1.f : v##i; \
                   float A = (v##i == smax) ? smax : v##i + smax; \
                   float qs = (A == 0.f) ? 1.f : A; \
                   float ft = Bsp / qm; \
                   float ft2 = Bco / qs; \
                   float cont = loww[(i)] * ft + high0 * (1.f - ft) \
                              + loww[C + (i)] * ft2 + high1 * (1.f - ft2); \
                   out[(i) * HW + p] = u[(i) * HW + p] - pw##i - cont; }
    REP21(CONTQ)
#undef CONTQ
  } else {
    float cc = high0 + high1;
#define OUTW(i) out[(i) * HW + p] = u[(i) * HW + p] - pw##i - cc;
    REP21(OUTW)
#undef OUTW
  }
}

extern "C" void kernel_launch(void* const* d_in, const int* in_sizes, int n_in,
                              void* d_out, int out_size, void* d_ws, size_t ws_size,
                              hipStream_t stream) {
  const float* unaries = (const float*)d_in[0];
  const int* sp_map = (const int*)d_in[2];
  const float* skw = (const float*)d_in[3];
  const float* bkw = (const float*)d_in[4];
  const float* loww = (const float*)d_in[5];
  const float* highw = (const float*)d_in[6];
  const float* cm = (const float*)d_in[7];
  float* out = (float*)d_out;
  float* ws = (float*)d_ws;
  float* smb = ws + SM_OFF;
  float* vsp = ws + VSP_OFF;
  float* vbi = ws + VBI_OFF;
  int* spt = (int*)(ws + SPT_OFF);
  float* ubuf = ws + UB_OFF;
  float* qbuf = ws + QB_OFF;
  int* ncond = (int*)(ws + NCOND_OFF);
  int* list = (int*)(ws + LIST_OFF);

  k_setup<<<1, 512, 0, stream>>>(ws, skw, bkw, cm);
  k_spt<<<HW / 256, 256, 0, stream>>>(sp_map, spt, ncond, list);
  k_tin<<<HW / 256, 256, 0, stream>>>(unaries, ubuf);
  for (int i = 0; i < N_ITERS; ++i) {
    int sp_id = 250 + 7 * i;
    const float* qin = (i == 0) ? ubuf : qbuf;
    k_softmax<<<HW / 256, 256, 0, stream>>>(qin, smb);
    k_clique<<<C, 256, 0, stream>>>(smb, ws, i);
    k_vblur<<<dim3(2, 64, C), 256, 0, stream>>>(smb, vsp, vbi, ws);
    k_hcombine<<<dim3(2, 512), 256, 0, stream>>>(vsp, vbi, smb, ubuf, spt, qbuf,
                                                 ws, loww, highw, sp_id, i);
  }
  k_tout<<<HW / 256, 256, 0, stream>>>(qbuf, out);
}